// Round 6
// baseline (297.659 us; speedup 1.0000x reference)
//
#include <hip/hip_runtime.h>
#include <hip/hip_bf16.h>

typedef __bf16 bf16_t;
typedef __bf16 bf16x8 __attribute__((ext_vector_type(8)));
typedef __bf16 bf16x4 __attribute__((ext_vector_type(4)));
typedef float f32x4 __attribute__((ext_vector_type(4)));
typedef unsigned int u32;

#define NUM_USER 200000
#define NUM_ITEM 200000
#define DIM_E 64
#define DIM_FEAT 128
#define HID 256
#define BATCH 16384
#define GG 17
#define NN (BATCH * GG)   // 278528
#define NREP 139264       // int(NN * 0.5)
#define NWAVES 4096       // 512 blocks x 8 waves (target: 2 blocks/CU)
#define NSP 6250          // strip-pairs: 6250 * 32 == 200000
#define W1ROWS 240        // W1 rows staged in LDS; rows 240-255 stream from L1

// ---------------------------------------------------------------------------
// K1: transpose + bf16-cast weights, scatter mask.
//   W2t gets a static COLUMN PERMUTATION within each 32-col block:
//   position p = Q*8+j holds hidden k = 32b + Q*4 + (j&3) + 16*(j>>2),
//   matching phase-1's C-layout output order per lane-quad (no C->B shuffle).
// ---------------------------------------------------------------------------
__global__ __launch_bounds__(256) void prep3_kernel(
    const float* __restrict__ W1, const float* __restrict__ W2,
    const int* __restrict__ rand_index,
    bf16_t* __restrict__ W1t, bf16_t* __restrict__ W2t,
    unsigned char* __restrict__ mask)
{
    const int t = blockIdx.x * 256 + threadIdx.x;
    if (t < HID * DIM_FEAT) {            // W1t[n][k], n<256, k<128
        const int n = t >> 7, k = t & 127;
        W1t[t] = (bf16_t)W1[k * HID + n];
    }
    if (t < DIM_E * HID) {               // W2t[n][c], n<64, c<256 (k-permuted)
        const int n = t >> 8, c = t & 255;
        const int b = c >> 5, p = c & 31;
        const int Q = p >> 3, j = p & 7;
        const int k = b * 32 + Q * 4 + (j & 3) + ((j >> 2) << 4);
        W2t[t] = (bf16_t)W2[k * DIM_E + n];
    }
    if (t < NREP) mask[rand_index[t]] = 1;
}

// ---------------------------------------------------------------------------
// K2: encoder v13 — LDS squeezed under 64 KB/block to enable 2 blocks/CU:
//   round 5 showed 71 KB blocks do NOT co-schedule (pool < 142 KB, likely
//   128 KB usable), so: W1 unpadded + XOR-swizzled (byte ^= (row&7)<<4,
//   uniform 8-lane/16B-slot -> b128 minimum, no pad needed), only 240 of
//   256 rows staged (rows 240-255 = nt 15 tile, 4 KB, read from global,
//   L1-hot, wave-uniform branch). W2 streamed from global (32 KB, L1/L2).
//   LDS = 61440 + 1280 = 62720 B -> 2 x ~63 KB <= 128 KB pool.
//   (512,2) launch bounds: proven 128-VGPR budget, ~112 used, no spill.
// ---------------------------------------------------------------------------
__global__ __launch_bounds__(512, 2) void encoder13_kernel(
    const float* __restrict__ vfeat,
    const bf16_t* __restrict__ W1t, const float* __restrict__ b1v,
    const bf16_t* __restrict__ W2t, const float* __restrict__ b2v,
    bf16_t* __restrict__ featB)
{
    const int tid  = threadIdx.x;
    const int wave = tid >> 6;
    const int lane = tid & 63;
    const int r    = lane & 15;          // item-row within strip
    const int Q    = lane >> 4;          // quad

    __shared__ bf16_t w1s[W1ROWS * DIM_FEAT];  // 61440 B, XOR-swizzled
    __shared__ float  b1s[HID];                // 1024 B
    __shared__ float  b2s[DIM_E];              // 256 B  -> 62720 B total

    // ---- stage W1 rows [0,240) swizzled + biases, once ----
    for (int c = tid; c < W1ROWS * 16; c += 512) {   // 3840 uint4 chunks
        const int n = c >> 4, ks = c & 15;
        const int dst = (n << 8) + (((ks << 4)) ^ ((n & 7) << 4));
        *reinterpret_cast<uint4*>(reinterpret_cast<char*>(w1s) + dst) =
            reinterpret_cast<const uint4*>(W1t)[c];
    }
    if (tid < HID) b1s[tid] = b1v[tid];
    if (tid < DIM_E) b2s[tid] = b2v[tid];
    __syncthreads();                                // the only barrier

    // per-lane W2 base: row r (stride 256), col Q*8; n2 adds 16 rows, t adds 32 cols
    const bf16_t* w2base = W2t + r * HID + Q * 8;
    const int swz = (r & 7) << 4;

    int sp = blockIdx.x * 8 + wave;                 // strip-pair id

    float4 v0[2][4], v1[2][4];
    // initial prefetch
    {
        const size_t row0 = (size_t)sp * 32;
#pragma unroll
        for (int s = 0; s < 2; ++s) {
            const float* rp = vfeat + (row0 + s * 16 + r) * DIM_FEAT + Q * 8;
#pragma unroll
            for (int ks = 0; ks < 4; ++ks) {
                v0[s][ks] = *reinterpret_cast<const float4*>(rp + ks * 32);
                v1[s][ks] = *reinterpret_cast<const float4*>(rp + ks * 32 + 4);
            }
        }
    }

    while (sp < NSP) {
        const size_t row0 = (size_t)sp * 32;

        // ---- build normalized bf16 A-fragments from prefetched regs ----
        bf16x8 af[2][4];
#pragma unroll
        for (int s = 0; s < 2; ++s) {
            float ss = 0.f;
#pragma unroll
            for (int ks = 0; ks < 4; ++ks) {
                ss += v0[s][ks].x * v0[s][ks].x + v0[s][ks].y * v0[s][ks].y
                    + v0[s][ks].z * v0[s][ks].z + v0[s][ks].w * v0[s][ks].w;
                ss += v1[s][ks].x * v1[s][ks].x + v1[s][ks].y * v1[s][ks].y
                    + v1[s][ks].z * v1[s][ks].z + v1[s][ks].w * v1[s][ks].w;
            }
            ss += __shfl_xor(ss, 16, 64);
            ss += __shfl_xor(ss, 32, 64);
            const float inv = 1.0f / fmaxf(sqrtf(ss), 1e-12f);
#pragma unroll
            for (int ks = 0; ks < 4; ++ks) {
                bf16x8 v;
                v[0] = (bf16_t)(v0[s][ks].x * inv); v[1] = (bf16_t)(v0[s][ks].y * inv);
                v[2] = (bf16_t)(v0[s][ks].z * inv); v[3] = (bf16_t)(v0[s][ks].w * inv);
                v[4] = (bf16_t)(v1[s][ks].x * inv); v[5] = (bf16_t)(v1[s][ks].y * inv);
                v[6] = (bf16_t)(v1[s][ks].z * inv); v[7] = (bf16_t)(v1[s][ks].w * inv);
                af[s][ks] = v;
            }
        }

        // ---- prefetch next strip (latency hides under t-loop) ----
        const int spn = sp + NWAVES;
        if (spn < NSP) {
            const size_t nr0 = (size_t)spn * 32;
#pragma unroll
            for (int s = 0; s < 2; ++s) {
                const float* rp = vfeat + (nr0 + s * 16 + r) * DIM_FEAT + Q * 8;
#pragma unroll
                for (int ks = 0; ks < 4; ++ks) {
                    v0[s][ks] = *reinterpret_cast<const float4*>(rp + ks * 32);
                    v1[s][ks] = *reinterpret_cast<const float4*>(rp + ks * 32 + 4);
                }
            }
        }

        f32x4 acc2[2][4];
#pragma unroll
        for (int s = 0; s < 2; ++s)
#pragma unroll
            for (int n2 = 0; n2 < 4; ++n2) acc2[s][n2] = (f32x4){0.f, 0.f, 0.f, 0.f};

#pragma unroll 2
        for (int t = 0; t < 8; ++t) {
            // ---- W2 fragments for this t: stream from global (L1/L2-hot) ----
            bf16x8 w2f[4];
#pragma unroll
            for (int n2 = 0; n2 < 4; ++n2)
                w2f[n2] = *reinterpret_cast<const bf16x8*>(
                    w2base + n2 * 16 * HID + t * 32);

            // ---- phase 1: h-tiles 2t, 2t+1 (both strips) ----
            u32 pk[2][2][2];   // [strip][tileHalf][reg]
#pragma unroll
            for (int h = 0; h < 2; ++h) {
                const int nt = t * 2 + h;
                bf16x8 w1f[4];
                if (nt < 15) {       // wave-uniform branch: LDS, swizzled
                    const char* rowp =
                        reinterpret_cast<const char*>(w1s) + ((nt * 16 + r) << 8);
#pragma unroll
                    for (int ks = 0; ks < 4; ++ks)
                        w1f[ks] = *reinterpret_cast<const bf16x8*>(
                            rowp + (((Q << 4) + (ks << 6)) ^ swz));
                } else {             // rows 240-255: global, 4 KB L1-resident
                    const bf16_t* gp = W1t + (240 + r) * DIM_FEAT + Q * 8;
#pragma unroll
                    for (int ks = 0; ks < 4; ++ks)
                        w1f[ks] = *reinterpret_cast<const bf16x8*>(gp + ks * 32);
                }
                const float4 bias1 = *reinterpret_cast<const float4*>(&b1s[nt * 16 + Q * 4]);
#pragma unroll
                for (int s = 0; s < 2; ++s) {
                    f32x4 a1 = (f32x4){0.f, 0.f, 0.f, 0.f};
#pragma unroll
                    for (int ks = 0; ks < 4; ++ks)
                        a1 = __builtin_amdgcn_mfma_f32_16x16x32_bf16(w1f[ks], af[s][ks], a1, 0, 0, 0);
                    bf16x4 hv4;
#pragma unroll
                    for (int i = 0; i < 4; ++i) {
                        float hv = a1[i] + ((const float*)&bias1)[i];
                        hv = hv >= 0.f ? hv : 0.01f * hv;
                        hv4[i] = (bf16_t)hv;
                    }
                    const uint2 u = __builtin_bit_cast(uint2, hv4);
                    pk[s][h][0] = u.x;
                    pk[s][h][1] = u.y;
                }
            }
            // ---- phase-2 MFMAs: hfrag is lane-local (no shuffles) ----
#pragma unroll
            for (int s = 0; s < 2; ++s) {
                uint4 bu;
                bu.x = pk[s][0][0];
                bu.y = pk[s][0][1];
                bu.z = pk[s][1][0];
                bu.w = pk[s][1][1];
                const bf16x8 hfrag = __builtin_bit_cast(bf16x8, bu);
#pragma unroll
                for (int n2 = 0; n2 < 4; ++n2)
                    acc2[s][n2] = __builtin_amdgcn_mfma_f32_16x16x32_bf16(w2f[n2], hfrag, acc2[s][n2], 0, 0, 0);
            }
        }

        // ---- epilogue: bias + packed bf16 stores ----
#pragma unroll
        for (int n2 = 0; n2 < 4; ++n2) {
            const float4 bias2 = *reinterpret_cast<const float4*>(&b2s[n2 * 16 + Q * 4]);
#pragma unroll
            for (int s = 0; s < 2; ++s) {
                bf16x4 o;
                o[0] = (bf16_t)(acc2[s][n2][0] + bias2.x);
                o[1] = (bf16_t)(acc2[s][n2][1] + bias2.y);
                o[2] = (bf16_t)(acc2[s][n2][2] + bias2.z);
                o[3] = (bf16_t)(acc2[s][n2][3] + bias2.w);
                *reinterpret_cast<bf16x4*>(
                    featB + (row0 + s * 16 + r) * DIM_E + n2 * 16 + Q * 4) = o;
            }
        }
        sp = spn;
    }
}

// ---------------------------------------------------------------------------
// K3: loss elements — 4-lane clusters, 2 elements/thread, bf16 feature
// ---------------------------------------------------------------------------
__global__ __launch_bounds__(256) void loss_elem4_kernel(
    const bf16_t* __restrict__ featB, const float* __restrict__ id_emb,
    const int* __restrict__ user_t, const int* __restrict__ item_t,
    const unsigned char* __restrict__ mask,
    float* __restrict__ s1, float* __restrict__ s2)
{
    const int kq = threadIdx.x & 3;              // dims [kq*16, kq*16+16)
    const int c  = blockIdx.x * 64 + (threadIdx.x >> 2);

#pragma unroll
    for (int half = 0; half < 2; ++half) {
        const int nn = c + half * (NN / 2);
        const int b  = nn / GG;
        const int u  = user_t[nn];
        const int it = item_t[nn];
        const int pos = item_t[b * GG];
        int fidx = min(max(it - NUM_USER, 0), NUM_ITEM - 1);
        const bool rep = mask[nn] != 0;

        const bf16x8* fp = reinterpret_cast<const bf16x8*>(featB + (size_t)fidx * DIM_E + kq * 16);
        const float4* pp = reinterpret_cast<const float4*>(id_emb + (size_t)pos * DIM_E) + kq * 4;
        const float4* up = reinterpret_cast<const float4*>(id_emb + (size_t)u   * DIM_E) + kq * 4;
        const float4* ip = reinterpret_cast<const float4*>(id_emb + (size_t)it  * DIM_E) + kq * 4;

        const bf16x8 f8a = fp[0];
        const bf16x8 f8b = fp[1];

        float x = 0.f, y = 0.f, z = 0.f, w = 0.f;
#pragma unroll
        for (int j = 0; j < 4; ++j) {
            const float4 p  = pp[j];
            const float4 uu = up[j];
            const float4 iv = ip[j];
            const bf16x8 fb = (j < 2) ? f8a : f8b;
            float f0 = (float)fb[(j & 1) * 4 + 0];
            float f1 = (float)fb[(j & 1) * 4 + 1];
            float f2 = (float)fb[(j & 1) * 4 + 2];
            float f3 = (float)fb[(j & 1) * 4 + 3];
            const float a0 = rep ? f0 : iv.x;
            const float a1 = rep ? f1 : iv.y;
            const float a2 = rep ? f2 : iv.z;
            const float a3 = rep ? f3 : iv.w;
            x += f0 * f0 + f1 * f1 + f2 * f2 + f3 * f3;
            y += p.x * p.x + p.y * p.y + p.z * p.z + p.w * p.w;
            z += p.x * f0 + p.y * f1 + p.z * f2 + p.w * f3;
            w += uu.x * a0 + uu.y * a1 + uu.z * a2 + uu.w * a3;
        }
#pragma unroll
        for (int off = 1; off <= 2; off <<= 1) {
            x += __shfl_xor(x, off, 64);
            y += __shfl_xor(y, off, 64);
            z += __shfl_xor(z, off, 64);
            w += __shfl_xor(w, off, 64);
        }
        if (kq == 0) {
            const float dot1 = z / (fmaxf(sqrtf(x), 1e-12f) * fmaxf(sqrtf(y), 1e-12f));
            s1[nn] = __expf(dot1 * 5.0f);   // 1/TEMP = 5
            s2[nn] = __expf(w * 5.0f);
        }
    }
}

// ---------------------------------------------------------------------------
// K4: per-b softmax-style loss + block reduce + single atomicAdd to d_out
// ---------------------------------------------------------------------------
__global__ __launch_bounds__(256) void loss_reduce_kernel(
    const float* __restrict__ s1, const float* __restrict__ s2,
    float* __restrict__ out)
{
    const int b = blockIdx.x * 256 + threadIdx.x;  // 64*256 == 16384 exactly
    float tot1 = 0.f, tot2 = 0.f, p1 = 0.f, p2 = 0.f;
#pragma unroll
    for (int g = 0; g < GG; ++g) {
        const float a1 = s1[b * GG + g];
        const float a2 = s2[b * GG + g];
        if (g == 0) { p1 = a1; p2 = a2; }
        tot1 += a1; tot2 += a2;
    }
    const float l1 = -logf(p1 / (tot1 + 1e-8f) + 1e-8f);
    const float l2 = -logf(p2 / (tot2 + 1e-8f) + 1e-8f);
    float v = 0.5f * l1 + 0.5f * l2;
#pragma unroll
    for (int off = 32; off > 0; off >>= 1) v += __shfl_xor(v, off, 64);
    __shared__ float red[4];
    const int wave = threadIdx.x >> 6, lane = threadIdx.x & 63;
    if (lane == 0) red[wave] = v;
    __syncthreads();
    if (threadIdx.x == 0)
        atomicAdd(out, (red[0] + red[1] + red[2] + red[3]) * (1.0f / BATCH));
}

// ---------------------------------------------------------------------------
extern "C" void kernel_launch(void* const* d_in, const int* in_sizes, int n_in,
                              void* d_out, int out_size, void* d_ws, size_t ws_size,
                              hipStream_t stream)
{
    (void)in_sizes; (void)n_in; (void)out_size; (void)ws_size;
    const float* v_feat    = (const float*)d_in[0];
    const float* id_emb    = (const float*)d_in[1];
    const float* W1        = (const float*)d_in[2];
    const float* b1        = (const float*)d_in[3];
    const float* W2        = (const float*)d_in[4];
    const float* b2        = (const float*)d_in[5];
    const int*   user_t    = (const int*)d_in[6];
    const int*   item_t    = (const int*)d_in[7];
    const int*   rand_idx  = (const int*)d_in[8];

    char* ws = (char*)d_ws;
    bf16_t*        W1t      = (bf16_t*)(ws + 0);             // 65536
    bf16_t*        W2t      = (bf16_t*)(ws + 65536);         // 32768
    unsigned char* mask     = (unsigned char*)(ws + 98304);  // 278528
    float*         s1       = (float*)(ws + 376832);         // 1114112
    float*         s2       = (float*)(ws + 1490944);        // 1114112
    bf16_t*        featB    = (bf16_t*)(ws + 2605056);       // 25600000

    hipMemsetAsync(mask, 0, NN, stream);
    hipMemsetAsync(d_out, 0, sizeof(float), stream);
    prep3_kernel<<<544, 256, 0, stream>>>(W1, W2, rand_idx, W1t, W2t, mask);
    encoder13_kernel<<<512, 512, 0, stream>>>(v_feat, W1t, b1, W2t, b2, featB);
    loss_elem4_kernel<<<2176, 256, 0, stream>>>(featB, id_emb, user_t, item_t, mask, s1, s2);
    loss_reduce_kernel<<<64, 256, 0, stream>>>(s1, s2, (float*)d_out);
}

// Round 7
// 268.757 us; speedup vs baseline: 1.1075x; 1.1075x over previous
//
#include <hip/hip_runtime.h>
#include <hip/hip_bf16.h>

typedef __bf16 bf16_t;
typedef __bf16 bf16x8 __attribute__((ext_vector_type(8)));
typedef __bf16 bf16x4 __attribute__((ext_vector_type(4)));
typedef float f32x4 __attribute__((ext_vector_type(4)));
typedef unsigned int u32;

#define NUM_USER 200000
#define NUM_ITEM 200000
#define DIM_E 64
#define DIM_FEAT 128
#define HID 256
#define BATCH 16384
#define GG 17
#define NN (BATCH * GG)   // 278528
#define NREP 139264       // int(NN * 0.5)
#define W1LP 136          // W1 LDS pitch (bf16): 68 words -> bank shift 4/row
#define W2LP 264          // W2 LDS pitch (bf16): 132 words -> bank shift 4/row
#define NWAVES 2048       // 256 blocks x 8 waves (proven encoder6/10 shape)
#define NSP 6250          // strip-pairs: 6250 * 32 == 200000

// ---------------------------------------------------------------------------
// K1: transpose + bf16-cast weights, scatter mask.
//   W2t gets a static COLUMN PERMUTATION within each 32-col block:
//   position p = Q*8+j holds hidden k = 32b + Q*4 + (j&3) + 16*(j>>2),
//   matching phase-1's C-layout output order per lane-quad (no C->B shuffle).
// ---------------------------------------------------------------------------
__global__ __launch_bounds__(256) void prep3_kernel(
    const float* __restrict__ W1, const float* __restrict__ W2,
    const int* __restrict__ rand_index,
    bf16_t* __restrict__ W1t, bf16_t* __restrict__ W2t,
    unsigned char* __restrict__ mask)
{
    const int t = blockIdx.x * 256 + threadIdx.x;
    if (t < HID * DIM_FEAT) {            // W1t[n][k], n<256, k<128
        const int n = t >> 7, k = t & 127;
        W1t[t] = (bf16_t)W1[k * HID + n];
    }
    if (t < DIM_E * HID) {               // W2t[n][c], n<64, c<256 (k-permuted)
        const int n = t >> 8, c = t & 255;
        const int b = c >> 5, p = c & 31;
        const int Q = p >> 3, j = p & 7;
        const int k = b * 32 + Q * 4 + (j & 3) + ((j >> 2) << 4);
        W2t[t] = (bf16_t)W2[k * DIM_E + n];
    }
    if (t < NREP) mask[rand_index[t]] = 1;
}

// ---------------------------------------------------------------------------
// K2: encoder v10 (round-4 proven: 65.7 us, VGPR 100, no spill).
//   512 thr, (512,2), W1+W2 LDS-resident, one barrier, shuffle-free
//   phase-2 via the prep3 W2 column permutation. Occupancy axis closed:
//   rounds 1-3 (1024-thr blocks) and 5-6 (LDS squeeze to 63 KB) all failed
//   to raise resident waves/SIMD above 2 — keep the known-best shape.
// ---------------------------------------------------------------------------
__global__ __launch_bounds__(512, 2) void encoder10_kernel(
    const float* __restrict__ vfeat,
    const bf16_t* __restrict__ W1t, const float* __restrict__ b1v,
    const bf16_t* __restrict__ W2t, const float* __restrict__ b2v,
    bf16_t* __restrict__ featB)
{
    const int tid  = threadIdx.x;
    const int wave = tid >> 6;
    const int lane = tid & 63;
    const int r    = lane & 15;          // item-row within strip
    const int Q    = lane >> 4;          // quad

    __shared__ bf16_t w1s[256 * W1LP];   // 69632 B
    __shared__ bf16_t w2s[64 * W2LP];    // 33792 B
    __shared__ float  b1s[HID];
    __shared__ float  b2s[DIM_E];

    // ---- stage weights once ----
    for (int c = tid; c < 4096; c += 512) {        // W1t: 4096 uint4
        const int n = c >> 4, ks = c & 15;
        *reinterpret_cast<uint4*>(&w1s[n * W1LP + ks * 8]) =
            reinterpret_cast<const uint4*>(W1t)[c];
    }
    for (int c = tid; c < 2048; c += 512) {        // W2t: 2048 uint4
        const int n = c >> 5, ks = c & 31;
        *reinterpret_cast<uint4*>(&w2s[n * W2LP + ks * 8]) =
            reinterpret_cast<const uint4*>(W2t)[c];
    }
    if (tid < HID) b1s[tid] = b1v[tid];
    if (tid < DIM_E) b2s[tid] = b2v[tid];
    __syncthreads();                                // the only barrier

    int sp = blockIdx.x * 8 + wave;                 // strip-pair id

    float4 v0[2][4], v1[2][4];
    // initial prefetch
    {
        const size_t row0 = (size_t)sp * 32;
#pragma unroll
        for (int s = 0; s < 2; ++s) {
            const float* rp = vfeat + (row0 + s * 16 + r) * DIM_FEAT + Q * 8;
#pragma unroll
            for (int ks = 0; ks < 4; ++ks) {
                v0[s][ks] = *reinterpret_cast<const float4*>(rp + ks * 32);
                v1[s][ks] = *reinterpret_cast<const float4*>(rp + ks * 32 + 4);
            }
        }
    }

    while (sp < NSP) {
        const size_t row0 = (size_t)sp * 32;

        // ---- build normalized bf16 A-fragments from prefetched regs ----
        bf16x8 af[2][4];
#pragma unroll
        for (int s = 0; s < 2; ++s) {
            float ss = 0.f;
#pragma unroll
            for (int ks = 0; ks < 4; ++ks) {
                ss += v0[s][ks].x * v0[s][ks].x + v0[s][ks].y * v0[s][ks].y
                    + v0[s][ks].z * v0[s][ks].z + v0[s][ks].w * v0[s][ks].w;
                ss += v1[s][ks].x * v1[s][ks].x + v1[s][ks].y * v1[s][ks].y
                    + v1[s][ks].z * v1[s][ks].z + v1[s][ks].w * v1[s][ks].w;
            }
            ss += __shfl_xor(ss, 16, 64);
            ss += __shfl_xor(ss, 32, 64);
            const float inv = 1.0f / fmaxf(sqrtf(ss), 1e-12f);
#pragma unroll
            for (int ks = 0; ks < 4; ++ks) {
                bf16x8 v;
                v[0] = (bf16_t)(v0[s][ks].x * inv); v[1] = (bf16_t)(v0[s][ks].y * inv);
                v[2] = (bf16_t)(v0[s][ks].z * inv); v[3] = (bf16_t)(v0[s][ks].w * inv);
                v[4] = (bf16_t)(v1[s][ks].x * inv); v[5] = (bf16_t)(v1[s][ks].y * inv);
                v[6] = (bf16_t)(v1[s][ks].z * inv); v[7] = (bf16_t)(v1[s][ks].w * inv);
                af[s][ks] = v;
            }
        }

        // ---- prefetch next strip (latency hides under t-loop) ----
        const int spn = sp + NWAVES;
        if (spn < NSP) {
            const size_t nr0 = (size_t)spn * 32;
#pragma unroll
            for (int s = 0; s < 2; ++s) {
                const float* rp = vfeat + (nr0 + s * 16 + r) * DIM_FEAT + Q * 8;
#pragma unroll
                for (int ks = 0; ks < 4; ++ks) {
                    v0[s][ks] = *reinterpret_cast<const float4*>(rp + ks * 32);
                    v1[s][ks] = *reinterpret_cast<const float4*>(rp + ks * 32 + 4);
                }
            }
        }

        f32x4 acc2[2][4];
#pragma unroll
        for (int s = 0; s < 2; ++s)
#pragma unroll
            for (int n2 = 0; n2 < 4; ++n2) acc2[s][n2] = (f32x4){0.f, 0.f, 0.f, 0.f};

#pragma unroll 2
        for (int t = 0; t < 8; ++t) {
            // ---- phase 1: h-tiles 2t, 2t+1 (both strips), from LDS W1 ----
            u32 pk[2][2][2];   // [strip][tileHalf][reg]
#pragma unroll
            for (int h = 0; h < 2; ++h) {
                const int nt = t * 2 + h;
                const bf16_t* bp = &w1s[(nt * 16 + r) * W1LP + Q * 8];
                bf16x8 w1f[4];
#pragma unroll
                for (int ks = 0; ks < 4; ++ks)
                    w1f[ks] = *reinterpret_cast<const bf16x8*>(bp + ks * 32);
                const float4 bias1 = *reinterpret_cast<const float4*>(&b1s[nt * 16 + Q * 4]);
#pragma unroll
                for (int s = 0; s < 2; ++s) {
                    f32x4 a1 = (f32x4){0.f, 0.f, 0.f, 0.f};
#pragma unroll
                    for (int ks = 0; ks < 4; ++ks)
                        a1 = __builtin_amdgcn_mfma_f32_16x16x32_bf16(w1f[ks], af[s][ks], a1, 0, 0, 0);
                    bf16x4 hv4;
#pragma unroll
                    for (int i = 0; i < 4; ++i) {
                        float hv = a1[i] + ((const float*)&bias1)[i];
                        hv = hv >= 0.f ? hv : 0.01f * hv;
                        hv4[i] = (bf16_t)hv;
                    }
                    const uint2 u = __builtin_bit_cast(uint2, hv4);
                    pk[s][h][0] = u.x;
                    pk[s][h][1] = u.y;
                }
            }
            // ---- W2 fragments for k in [32t, 32t+32) from LDS (k-permuted) ----
            bf16x8 w2f[4];
#pragma unroll
            for (int n2 = 0; n2 < 4; ++n2)
                w2f[n2] = *reinterpret_cast<const bf16x8*>(
                    &w2s[(n2 * 16 + r) * W2LP + t * 32 + Q * 8]);
            // ---- phase-2 MFMAs: hfrag is lane-local (no shuffles) ----
#pragma unroll
            for (int s = 0; s < 2; ++s) {
                uint4 bu;
                bu.x = pk[s][0][0];
                bu.y = pk[s][0][1];
                bu.z = pk[s][1][0];
                bu.w = pk[s][1][1];
                const bf16x8 hfrag = __builtin_bit_cast(bf16x8, bu);
#pragma unroll
                for (int n2 = 0; n2 < 4; ++n2)
                    acc2[s][n2] = __builtin_amdgcn_mfma_f32_16x16x32_bf16(w2f[n2], hfrag, acc2[s][n2], 0, 0, 0);
            }
        }

        // ---- epilogue: bias + packed bf16 stores ----
#pragma unroll
        for (int n2 = 0; n2 < 4; ++n2) {
            const float4 bias2 = *reinterpret_cast<const float4*>(&b2s[n2 * 16 + Q * 4]);
#pragma unroll
            for (int s = 0; s < 2; ++s) {
                bf16x4 o;
                o[0] = (bf16_t)(acc2[s][n2][0] + bias2.x);
                o[1] = (bf16_t)(acc2[s][n2][1] + bias2.y);
                o[2] = (bf16_t)(acc2[s][n2][2] + bias2.z);
                o[3] = (bf16_t)(acc2[s][n2][3] + bias2.w);
                *reinterpret_cast<bf16x4*>(
                    featB + (row0 + s * 16 + r) * DIM_E + n2 * 16 + Q * 4) = o;
            }
        }
        sp = spn;
    }
}

// ---------------------------------------------------------------------------
// K3 (fused K3+K4): one 8-lane cluster per batch element b.
//   lanes: kq = lane&3 covers dims [kq*16, kq*16+16); par = (lane>>2)&1
//   splits the 17 group elements even/odd (9 vs 8 serial steps).
//   The positive row id_emb[pos] and its norm are loaded/computed ONCE
//   per b (was 17x) — kills ~67 MB of redundant gathers. The softmax-log
//   loss is finished in-kernel: butterfly combines + one atomicAdd per
//   block. s1/s2 buffers and the loss_reduce dispatch are gone.
// ---------------------------------------------------------------------------
__global__ __launch_bounds__(256) void loss_fused_kernel(
    const bf16_t* __restrict__ featB, const float* __restrict__ id_emb,
    const int* __restrict__ user_t, const int* __restrict__ item_t,
    const unsigned char* __restrict__ mask,
    float* __restrict__ out)
{
    const int lane = threadIdx.x & 63;
    const int kq   = lane & 3;
    const int par  = (lane >> 2) & 1;
    const int b    = blockIdx.x * 32 + (threadIdx.x >> 3);   // 512 blocks x 32

    // ---- positive row: load + norm once per b ----
    const int pos = item_t[b * GG];
    const float4* pp = reinterpret_cast<const float4*>(id_emb + (size_t)pos * DIM_E) + kq * 4;
    const float4 pr0 = pp[0], pr1 = pp[1], pr2 = pp[2], pr3 = pp[3];
    float y = pr0.x*pr0.x + pr0.y*pr0.y + pr0.z*pr0.z + pr0.w*pr0.w
            + pr1.x*pr1.x + pr1.y*pr1.y + pr1.z*pr1.z + pr1.w*pr1.w
            + pr2.x*pr2.x + pr2.y*pr2.y + pr2.z*pr2.z + pr2.w*pr2.w
            + pr3.x*pr3.x + pr3.y*pr3.y + pr3.z*pr3.z + pr3.w*pr3.w;
    y += __shfl_xor(y, 1, 64);
    y += __shfl_xor(y, 2, 64);
    const float ny = fmaxf(sqrtf(y), 1e-12f);

    float tot1 = 0.f, tot2 = 0.f, ps1 = 0.f, ps2 = 0.f;
    for (int g = par; g < GG; g += 2) {
        const int nn = b * GG + g;
        const int u  = user_t[nn];
        const int it = item_t[nn];
        const bool rep = mask[nn] != 0;
        const int fidx = min(max(it - NUM_USER, 0), NUM_ITEM - 1);

        const bf16x8* fp = reinterpret_cast<const bf16x8*>(
            featB + (size_t)fidx * DIM_E + kq * 16);
        const float4* up = reinterpret_cast<const float4*>(id_emb + (size_t)u  * DIM_E) + kq * 4;
        const float4* ip = reinterpret_cast<const float4*>(id_emb + (size_t)it * DIM_E) + kq * 4;
        const bf16x8 f8a = fp[0];
        const bf16x8 f8b = fp[1];

        float x = 0.f, z = 0.f, w = 0.f;
#pragma unroll
        for (int j = 0; j < 4; ++j) {
            const float4 pv = (j == 0) ? pr0 : (j == 1) ? pr1 : (j == 2) ? pr2 : pr3;
            const float4 uu = up[j];
            const float4 iv = ip[j];
            const bf16x8 fb = (j < 2) ? f8a : f8b;
            const float f0 = (float)fb[(j & 1) * 4 + 0];
            const float f1 = (float)fb[(j & 1) * 4 + 1];
            const float f2 = (float)fb[(j & 1) * 4 + 2];
            const float f3 = (float)fb[(j & 1) * 4 + 3];
            const float a0 = rep ? f0 : iv.x;
            const float a1 = rep ? f1 : iv.y;
            const float a2 = rep ? f2 : iv.z;
            const float a3 = rep ? f3 : iv.w;
            x += f0 * f0 + f1 * f1 + f2 * f2 + f3 * f3;
            z += pv.x * f0 + pv.y * f1 + pv.z * f2 + pv.w * f3;
            w += uu.x * a0 + uu.y * a1 + uu.z * a2 + uu.w * a3;
        }
        x += __shfl_xor(x, 1, 64); x += __shfl_xor(x, 2, 64);
        z += __shfl_xor(z, 1, 64); z += __shfl_xor(z, 2, 64);
        w += __shfl_xor(w, 1, 64); w += __shfl_xor(w, 2, 64);

        const float dot1 = z / (fmaxf(sqrtf(x), 1e-12f) * ny);
        const float e1 = __expf(dot1 * 5.0f);   // 1/TEMP = 5
        const float e2 = __expf(w * 5.0f);
        if (g == 0) { ps1 = e1; ps2 = e2; }
        tot1 += e1; tot2 += e2;
    }
    // combine even/odd halves
    tot1 += __shfl_xor(tot1, 4, 64);
    tot2 += __shfl_xor(tot2, 4, 64);

    float v = 0.f;
    if ((lane & 7) == 0) {                      // kq==0 && par==0: has ps1/ps2
        const float l1 = -logf(ps1 / (tot1 + 1e-8f) + 1e-8f);
        const float l2 = -logf(ps2 / (tot2 + 1e-8f) + 1e-8f);
        v = 0.5f * l1 + 0.5f * l2;
    }
    v += __shfl_xor(v, 8, 64);
    v += __shfl_xor(v, 16, 64);
    v += __shfl_xor(v, 32, 64);

    __shared__ float red[4];
    const int wv = threadIdx.x >> 6;
    if (lane == 0) red[wv] = v;
    __syncthreads();
    if (threadIdx.x == 0)
        atomicAdd(out, (red[0] + red[1] + red[2] + red[3]) * (1.0f / BATCH));
}

// ---------------------------------------------------------------------------
extern "C" void kernel_launch(void* const* d_in, const int* in_sizes, int n_in,
                              void* d_out, int out_size, void* d_ws, size_t ws_size,
                              hipStream_t stream)
{
    (void)in_sizes; (void)n_in; (void)out_size; (void)ws_size;
    const float* v_feat    = (const float*)d_in[0];
    const float* id_emb    = (const float*)d_in[1];
    const float* W1        = (const float*)d_in[2];
    const float* b1        = (const float*)d_in[3];
    const float* W2        = (const float*)d_in[4];
    const float* b2        = (const float*)d_in[5];
    const int*   user_t    = (const int*)d_in[6];
    const int*   item_t    = (const int*)d_in[7];
    const int*   rand_idx  = (const int*)d_in[8];

    char* ws = (char*)d_ws;
    bf16_t*        W1t      = (bf16_t*)(ws + 0);             // 65536
    bf16_t*        W2t      = (bf16_t*)(ws + 65536);         // 32768
    unsigned char* mask     = (unsigned char*)(ws + 98304);  // 278528
    bf16_t*        featB    = (bf16_t*)(ws + 2605056);       // 25600000

    hipMemsetAsync(mask, 0, NN, stream);
    hipMemsetAsync(d_out, 0, sizeof(float), stream);
    prep3_kernel<<<544, 256, 0, stream>>>(W1, W2, rand_idx, W1t, W2t, mask);
    encoder10_kernel<<<256, 512, 0, stream>>>(v_feat, W1t, b1, W2t, b2, featB);
    loss_fused_kernel<<<512, 256, 0, stream>>>(featB, id_emb, user_t, item_t, mask, (float*)d_out);
}

// Round 8
// 259.055 us; speedup vs baseline: 1.1490x; 1.0375x over previous
//
#include <hip/hip_runtime.h>
#include <hip/hip_bf16.h>

typedef __bf16 bf16_t;
typedef __bf16 bf16x8 __attribute__((ext_vector_type(8)));
typedef __bf16 bf16x4 __attribute__((ext_vector_type(4)));
typedef float f32x4 __attribute__((ext_vector_type(4)));
typedef unsigned int u32;

#define NUM_USER 200000
#define NUM_ITEM 200000
#define DIM_E 64
#define DIM_FEAT 128
#define HID 256
#define BATCH 16384
#define GG 17
#define NN (BATCH * GG)   // 278528
#define NREP 139264       // int(NN * 0.5)
#define W1LP 136          // W1 LDS pitch (bf16): 68 words -> bank shift 4/row
#define W2LP 264          // W2 LDS pitch (bf16): 132 words -> bank shift 4/row
#define NWAVES 2048       // 256 blocks x 8 waves (proven shape; 1 block/CU)
#define NSP 12500         // 16-row strips: 12500 * 16 == 200000
                          // (was 6250 pairs: 3.05/wave -> 4-pass tail, 76% util;
                          //  now 6.1/wave -> 7-pass tail, 87% util)

// ---------------------------------------------------------------------------
// K1: transpose + bf16-cast weights, scatter mask.
//   W2t gets a static COLUMN PERMUTATION within each 32-col block:
//   position p = Q*8+j holds hidden k = 32b + Q*4 + (j&3) + 16*(j>>2),
//   matching phase-1's C-layout output order per lane-quad (no C->B shuffle).
// ---------------------------------------------------------------------------
__global__ __launch_bounds__(256) void prep3_kernel(
    const float* __restrict__ W1, const float* __restrict__ W2,
    const int* __restrict__ rand_index,
    bf16_t* __restrict__ W1t, bf16_t* __restrict__ W2t,
    unsigned char* __restrict__ mask)
{
    const int t = blockIdx.x * 256 + threadIdx.x;
    if (t < HID * DIM_FEAT) {            // W1t[n][k], n<256, k<128
        const int n = t >> 7, k = t & 127;
        W1t[t] = (bf16_t)W1[k * HID + n];
    }
    if (t < DIM_E * HID) {               // W2t[n][c], n<64, c<256 (k-permuted)
        const int n = t >> 8, c = t & 255;
        const int b = c >> 5, p = c & 31;
        const int Q = p >> 3, j = p & 7;
        const int k = b * 32 + Q * 4 + (j & 3) + ((j >> 2) << 4);
        W2t[t] = (bf16_t)W2[k * DIM_E + n];
    }
    if (t < NREP) mask[rand_index[t]] = 1;
}

// ---------------------------------------------------------------------------
// K2: encoder v14 = proven v10 dataflow with 16-ROW strips (was 32-row
//   pairs). Tail rebalance: 12500 strips / 2048 waves = 6.1 -> 87% util
//   vs 3.05/4 = 76%. Prefetch regs halve (v0/v1: 8 float4). All LDS
//   layout / MFMA mapping / shuffle-free phase-2 unchanged.
// ---------------------------------------------------------------------------
__global__ __launch_bounds__(512, 2) void encoder14_kernel(
    const float* __restrict__ vfeat,
    const bf16_t* __restrict__ W1t, const float* __restrict__ b1v,
    const bf16_t* __restrict__ W2t, const float* __restrict__ b2v,
    bf16_t* __restrict__ featB)
{
    const int tid  = threadIdx.x;
    const int wave = tid >> 6;
    const int lane = tid & 63;
    const int r    = lane & 15;          // item-row within strip
    const int Q    = lane >> 4;          // quad

    __shared__ bf16_t w1s[256 * W1LP];   // 69632 B
    __shared__ bf16_t w2s[64 * W2LP];    // 33792 B
    __shared__ float  b1s[HID];
    __shared__ float  b2s[DIM_E];

    // ---- stage weights once ----
    for (int c = tid; c < 4096; c += 512) {        // W1t: 4096 uint4
        const int n = c >> 4, ks = c & 15;
        *reinterpret_cast<uint4*>(&w1s[n * W1LP + ks * 8]) =
            reinterpret_cast<const uint4*>(W1t)[c];
    }
    for (int c = tid; c < 2048; c += 512) {        // W2t: 2048 uint4
        const int n = c >> 5, ks = c & 31;
        *reinterpret_cast<uint4*>(&w2s[n * W2LP + ks * 8]) =
            reinterpret_cast<const uint4*>(W2t)[c];
    }
    if (tid < HID) b1s[tid] = b1v[tid];
    if (tid < DIM_E) b2s[tid] = b2v[tid];
    __syncthreads();                                // the only barrier

    int sp = blockIdx.x * 8 + wave;                 // strip id (16 rows)

    float4 v0[4], v1[4];
    {
        const float* rp = vfeat + ((size_t)sp * 16 + r) * DIM_FEAT + Q * 8;
#pragma unroll
        for (int ks = 0; ks < 4; ++ks) {
            v0[ks] = *reinterpret_cast<const float4*>(rp + ks * 32);
            v1[ks] = *reinterpret_cast<const float4*>(rp + ks * 32 + 4);
        }
    }

    while (sp < NSP) {
        const size_t row0 = (size_t)sp * 16;

        // ---- build normalized bf16 A-fragments from prefetched regs ----
        bf16x8 af[4];
        {
            float ss = 0.f;
#pragma unroll
            for (int ks = 0; ks < 4; ++ks) {
                ss += v0[ks].x * v0[ks].x + v0[ks].y * v0[ks].y
                    + v0[ks].z * v0[ks].z + v0[ks].w * v0[ks].w;
                ss += v1[ks].x * v1[ks].x + v1[ks].y * v1[ks].y
                    + v1[ks].z * v1[ks].z + v1[ks].w * v1[ks].w;
            }
            ss += __shfl_xor(ss, 16, 64);
            ss += __shfl_xor(ss, 32, 64);
            const float inv = 1.0f / fmaxf(sqrtf(ss), 1e-12f);
#pragma unroll
            for (int ks = 0; ks < 4; ++ks) {
                bf16x8 v;
                v[0] = (bf16_t)(v0[ks].x * inv); v[1] = (bf16_t)(v0[ks].y * inv);
                v[2] = (bf16_t)(v0[ks].z * inv); v[3] = (bf16_t)(v0[ks].w * inv);
                v[4] = (bf16_t)(v1[ks].x * inv); v[5] = (bf16_t)(v1[ks].y * inv);
                v[6] = (bf16_t)(v1[ks].z * inv); v[7] = (bf16_t)(v1[ks].w * inv);
                af[ks] = v;
            }
        }

        // ---- prefetch next strip (latency hides under t-loop) ----
        const int spn = sp + NWAVES;
        if (spn < NSP) {
            const float* rp = vfeat + ((size_t)spn * 16 + r) * DIM_FEAT + Q * 8;
#pragma unroll
            for (int ks = 0; ks < 4; ++ks) {
                v0[ks] = *reinterpret_cast<const float4*>(rp + ks * 32);
                v1[ks] = *reinterpret_cast<const float4*>(rp + ks * 32 + 4);
            }
        }

        f32x4 acc2[4];
#pragma unroll
        for (int n2 = 0; n2 < 4; ++n2) acc2[n2] = (f32x4){0.f, 0.f, 0.f, 0.f};

#pragma unroll 2
        for (int t = 0; t < 8; ++t) {
            // ---- phase 1: h-tiles 2t, 2t+1 from LDS W1 ----
            u32 pk[2][2];   // [tileHalf][reg]
#pragma unroll
            for (int h = 0; h < 2; ++h) {
                const int nt = t * 2 + h;
                const bf16_t* bp = &w1s[(nt * 16 + r) * W1LP + Q * 8];
                bf16x8 w1f[4];
#pragma unroll
                for (int ks = 0; ks < 4; ++ks)
                    w1f[ks] = *reinterpret_cast<const bf16x8*>(bp + ks * 32);
                const float4 bias1 = *reinterpret_cast<const float4*>(&b1s[nt * 16 + Q * 4]);
                f32x4 a1 = (f32x4){0.f, 0.f, 0.f, 0.f};
#pragma unroll
                for (int ks = 0; ks < 4; ++ks)
                    a1 = __builtin_amdgcn_mfma_f32_16x16x32_bf16(w1f[ks], af[ks], a1, 0, 0, 0);
                bf16x4 hv4;
#pragma unroll
                for (int i = 0; i < 4; ++i) {
                    float hv = a1[i] + ((const float*)&bias1)[i];
                    hv = hv >= 0.f ? hv : 0.01f * hv;
                    hv4[i] = (bf16_t)hv;
                }
                const uint2 u = __builtin_bit_cast(uint2, hv4);
                pk[h][0] = u.x;
                pk[h][1] = u.y;
            }
            // ---- W2 fragments for k in [32t, 32t+32) from LDS (k-permuted) ----
            bf16x8 w2f[4];
#pragma unroll
            for (int n2 = 0; n2 < 4; ++n2)
                w2f[n2] = *reinterpret_cast<const bf16x8*>(
                    &w2s[(n2 * 16 + r) * W2LP + t * 32 + Q * 8]);
            // ---- phase-2 MFMAs: hfrag is lane-local (no shuffles) ----
            uint4 bu;
            bu.x = pk[0][0];
            bu.y = pk[0][1];
            bu.z = pk[1][0];
            bu.w = pk[1][1];
            const bf16x8 hfrag = __builtin_bit_cast(bf16x8, bu);
#pragma unroll
            for (int n2 = 0; n2 < 4; ++n2)
                acc2[n2] = __builtin_amdgcn_mfma_f32_16x16x32_bf16(w2f[n2], hfrag, acc2[n2], 0, 0, 0);
        }

        // ---- epilogue: bias + packed bf16 stores ----
#pragma unroll
        for (int n2 = 0; n2 < 4; ++n2) {
            const float4 bias2 = *reinterpret_cast<const float4*>(&b2s[n2 * 16 + Q * 4]);
            bf16x4 o;
            o[0] = (bf16_t)(acc2[n2][0] + bias2.x);
            o[1] = (bf16_t)(acc2[n2][1] + bias2.y);
            o[2] = (bf16_t)(acc2[n2][2] + bias2.z);
            o[3] = (bf16_t)(acc2[n2][3] + bias2.w);
            *reinterpret_cast<bf16x4*>(
                featB + (row0 + r) * DIM_E + n2 * 16 + Q * 4) = o;
        }
        sp = spn;
    }
}

// ---------------------------------------------------------------------------
// K3 (fused loss): one 16-LANE cluster per batch element b.
//   kq = lane&3 covers dims [kq*16, kq*16+16); par = (lane>>2)&3 splits the
//   17 group elements 4 ways (5/4/4/4 serial steps — was 9/8 with 8-lane
//   clusters). Grid doubles to 1024 blocks -> 16 waves/CU (was 8): 2x TLP
//   against the gather latency chain. pos row loaded/normed once per b.
//   Loss finished in-kernel: butterfly + one atomicAdd per block.
// ---------------------------------------------------------------------------
__global__ __launch_bounds__(256) void loss_fused16_kernel(
    const bf16_t* __restrict__ featB, const float* __restrict__ id_emb,
    const int* __restrict__ user_t, const int* __restrict__ item_t,
    const unsigned char* __restrict__ mask,
    float* __restrict__ out)
{
    const int lane = threadIdx.x & 63;
    const int kq   = lane & 3;
    const int par  = (lane >> 2) & 3;
    const int b    = blockIdx.x * 16 + (threadIdx.x >> 4);   // 1024 blocks x 16

    // ---- positive row: load + norm once per b ----
    const int pos = item_t[b * GG];
    const float4* pp = reinterpret_cast<const float4*>(id_emb + (size_t)pos * DIM_E) + kq * 4;
    const float4 pr0 = pp[0], pr1 = pp[1], pr2 = pp[2], pr3 = pp[3];
    float y = pr0.x*pr0.x + pr0.y*pr0.y + pr0.z*pr0.z + pr0.w*pr0.w
            + pr1.x*pr1.x + pr1.y*pr1.y + pr1.z*pr1.z + pr1.w*pr1.w
            + pr2.x*pr2.x + pr2.y*pr2.y + pr2.z*pr2.z + pr2.w*pr2.w
            + pr3.x*pr3.x + pr3.y*pr3.y + pr3.z*pr3.z + pr3.w*pr3.w;
    y += __shfl_xor(y, 1, 64);
    y += __shfl_xor(y, 2, 64);
    const float ny = fmaxf(sqrtf(y), 1e-12f);

    float tot1 = 0.f, tot2 = 0.f, ps1 = 0.f, ps2 = 0.f;
    for (int g = par; g < GG; g += 4) {
        const int nn = b * GG + g;
        const int u  = user_t[nn];
        const int it = item_t[nn];
        const bool rep = mask[nn] != 0;
        const int fidx = min(max(it - NUM_USER, 0), NUM_ITEM - 1);

        const bf16x8* fp = reinterpret_cast<const bf16x8*>(
            featB + (size_t)fidx * DIM_E + kq * 16);
        const float4* up = reinterpret_cast<const float4*>(id_emb + (size_t)u  * DIM_E) + kq * 4;
        const float4* ip = reinterpret_cast<const float4*>(id_emb + (size_t)it * DIM_E) + kq * 4;
        const bf16x8 f8a = fp[0];
        const bf16x8 f8b = fp[1];

        float x = 0.f, z = 0.f, w = 0.f;
#pragma unroll
        for (int j = 0; j < 4; ++j) {
            const float4 pv = (j == 0) ? pr0 : (j == 1) ? pr1 : (j == 2) ? pr2 : pr3;
            const float4 uu = up[j];
            const float4 iv = ip[j];
            const bf16x8 fb = (j < 2) ? f8a : f8b;
            const float f0 = (float)fb[(j & 1) * 4 + 0];
            const float f1 = (float)fb[(j & 1) * 4 + 1];
            const float f2 = (float)fb[(j & 1) * 4 + 2];
            const float f3 = (float)fb[(j & 1) * 4 + 3];
            const float a0 = rep ? f0 : iv.x;
            const float a1 = rep ? f1 : iv.y;
            const float a2 = rep ? f2 : iv.z;
            const float a3 = rep ? f3 : iv.w;
            x += f0 * f0 + f1 * f1 + f2 * f2 + f3 * f3;
            z += pv.x * f0 + pv.y * f1 + pv.z * f2 + pv.w * f3;
            w += uu.x * a0 + uu.y * a1 + uu.z * a2 + uu.w * a3;
        }
        x += __shfl_xor(x, 1, 64); x += __shfl_xor(x, 2, 64);
        z += __shfl_xor(z, 1, 64); z += __shfl_xor(z, 2, 64);
        w += __shfl_xor(w, 1, 64); w += __shfl_xor(w, 2, 64);

        const float dot1 = z / (fmaxf(sqrtf(x), 1e-12f) * ny);
        const float e1 = __expf(dot1 * 5.0f);   // 1/TEMP = 5
        const float e2 = __expf(w * 5.0f);
        if (g == 0) { ps1 = e1; ps2 = e2; }
        tot1 += e1; tot2 += e2;
    }
    // combine the 4 par groups (within the 16-lane cluster)
    tot1 += __shfl_xor(tot1, 4, 64);  tot1 += __shfl_xor(tot1, 8, 64);
    tot2 += __shfl_xor(tot2, 4, 64);  tot2 += __shfl_xor(tot2, 8, 64);

    float v = 0.f;
    if ((lane & 15) == 0) {                     // kq==0 && par==0: has ps1/ps2
        const float l1 = -logf(ps1 / (tot1 + 1e-8f) + 1e-8f);
        const float l2 = -logf(ps2 / (tot2 + 1e-8f) + 1e-8f);
        v = 0.5f * l1 + 0.5f * l2;
    }
    v += __shfl_xor(v, 16, 64);
    v += __shfl_xor(v, 32, 64);

    __shared__ float red[4];
    const int wv = threadIdx.x >> 6;
    if (lane == 0) red[wv] = v;
    __syncthreads();
    if (threadIdx.x == 0)
        atomicAdd(out, (red[0] + red[1] + red[2] + red[3]) * (1.0f / BATCH));
}

// ---------------------------------------------------------------------------
extern "C" void kernel_launch(void* const* d_in, const int* in_sizes, int n_in,
                              void* d_out, int out_size, void* d_ws, size_t ws_size,
                              hipStream_t stream)
{
    (void)in_sizes; (void)n_in; (void)out_size; (void)ws_size;
    const float* v_feat    = (const float*)d_in[0];
    const float* id_emb    = (const float*)d_in[1];
    const float* W1        = (const float*)d_in[2];
    const float* b1        = (const float*)d_in[3];
    const float* W2        = (const float*)d_in[4];
    const float* b2        = (const float*)d_in[5];
    const int*   user_t    = (const int*)d_in[6];
    const int*   item_t    = (const int*)d_in[7];
    const int*   rand_idx  = (const int*)d_in[8];

    char* ws = (char*)d_ws;
    bf16_t*        W1t      = (bf16_t*)(ws + 0);             // 65536
    bf16_t*        W2t      = (bf16_t*)(ws + 65536);         // 32768
    unsigned char* mask     = (unsigned char*)(ws + 98304);  // 278528
    bf16_t*        featB    = (bf16_t*)(ws + 2605056);       // 25600000

    hipMemsetAsync(mask, 0, NN, stream);
    hipMemsetAsync(d_out, 0, sizeof(float), stream);
    prep3_kernel<<<544, 256, 0, stream>>>(W1, W2, rand_idx, W1t, W2t, mask);
    encoder14_kernel<<<256, 512, 0, stream>>>(v_feat, W1t, b1, W2t, b2, featB);
    loss_fused16_kernel<<<1024, 256, 0, stream>>>(featB, id_emb, user_t, item_t, mask, (float*)d_out);
}